// Round 8
// baseline (311.115 us; speedup 1.0000x reference)
//
#include <hip/hip_runtime.h>

// Conv2d + BN int8 quantized, MI355X gfx950. Inputs fp32, output fp32.
// R13: R12's 2-row merge spilled (demand ~130 regs > 128 cap: VGPR=64 +
// scratch traffic, WRITE 414MB). Keep the merge (staging -33%, A-traffic -50%,
// 16-MFMA chains), fix the spill:
//   - single-buffer B (JIT ds_read_b64 per step, proven in R9's 61us)
//   - A fragments JIT per tap, short-lived ap[4] inside the g-loop
//   - peak demand ~108 regs < 128 cap @ launch_bounds(256,4): no spill
//   - K-loop = 9-tap outer x 4-substep inner, all indices static
// quant kernels / swizzle / XCD chunking / static C/D map unchanged (proven).
// Host falls back to the proven R5 fused kernel if ws_size is too small.

#define BATCH 32
#define CIN   128
#define HH    56
#define WW    56
#define OCH   256

typedef __attribute__((ext_vector_type(4))) int int4v;
typedef __attribute__((ext_vector_type(2))) long longx2;

#define QX_BYTES (32 * 56 * 56 * 128)           // 12,845,056  qxp[b][h][w][c]
#define QW_BYTES (256 * 1152)                   // 294,912 (fragment-packed)
#define WS_NEEDED (QX_BYTES + QW_BYTES + 1024)

__device__ __forceinline__ void gload_lds16(const void* g, void* l) {
  __builtin_amdgcn_global_load_lds(
      (const __attribute__((address_space(1))) unsigned int*)g,
      (__attribute__((address_space(3))) unsigned int*)l, 16, 0, 0);
}

// ---------------- kernel 1: weight quantization + fragment pack ------------
// One block per output channel o. Layout (t-pair merged into long2):
//   byte ((og*36 + r*4 + c04)*128 + (l16*4+quad)*2 + t)*8 + (half*4+k)
//   holds channel c04*32+quad*8+half*4+k of o = og*32+t*16+l16 at tap r.
// Conv lane (l16,quad) loads long2 at longx2 index (r*4+c04)*64 + l16*4+quad:
//   [0] = t=0 operand, [1] = t=1 operand; wave chunk = contiguous 1KB.
__global__ __launch_bounds__(256) void quant_w_kernel(
    const float* __restrict__ w, const float* __restrict__ sxp,
    char* __restrict__ qwf, float* __restrict__ alpha) {
  __shared__ float wf[1152];
  __shared__ float red[256];
  const int o = blockIdx.x;
  const int tid = threadIdx.x;
  const float* wrow = w + (size_t)o * 1152;
  float m = 0.f;
  for (int i = tid; i < 288; i += 256) {
    const float4 v = ((const float4*)wrow)[i];
    ((float4*)wf)[i] = v;
    m = fmaxf(m, fmaxf(fmaxf(fabsf(v.x), fabsf(v.y)),
                       fmaxf(fabsf(v.z), fabsf(v.w))));
  }
  red[tid] = m;
  __syncthreads();
  for (int s = 128; s > 0; s >>= 1) {
    if (tid < s) red[tid] = fmaxf(red[tid], red[tid + s]);
    __syncthreads();
  }
  const float sc = red[0] / 127.0f;   // max/QMAX, fp32, matches reference
  if (tid == 0) alpha[o] = sc * sxp[0];
  if (tid < 36) {
    const int r = tid >> 2, c04 = tid & 3;
    const int og = o >> 5, t = (o >> 4) & 1, l16 = o & 15;
    unsigned int* base = (unsigned int*)(qwf + (size_t)og * 36864 +
                                         (size_t)(r * 4 + c04) * 1024);
#pragma unroll
    for (int quad = 0; quad < 4; ++quad) {
#pragma unroll
      for (int half = 0; half < 2; ++half) {
        unsigned int pk = 0;
#pragma unroll
        for (int k = 0; k < 4; ++k) {
          const int c = c04 * 32 + quad * 8 + half * 4 + k;
          const int q =
              (int)fminf(127.f, fmaxf(-127.f, rintf(wf[c * 9 + r] / sc)));
          pk |= ((unsigned int)(q & 255)) << (8 * k);
        }
        base[(l16 * 4 + quad) * 4 + t * 2 + half] = pk;
      }
    }
  }
}

// ---------------- kernel 2: x quantization -> swizzled im2col rows ---------
// qxp byte ((b*56+h)*56 + w)*128 + j holds q(x[b][ j^(((w+1)&15)<<3) ][h][w]).
__global__ __launch_bounds__(256) void quant_x_kernel(
    const float* __restrict__ x, const float* __restrict__ sxp,
    unsigned int* __restrict__ qxp) {
  __shared__ char ldsA[128 * 60];   // [c][w] quantized bytes, stride 60
  const int row = blockIdx.x;       // b*56 + h
  const int b = row / 56, h = row % 56;
  const float sx = sxp[0];
  for (int i = threadIdx.x; i < 1792; i += 256) {
    const int c = i / 14, f = i % 14;
    const float4 v =
        *(const float4*)(x + (((size_t)b * 128 + c) * 56 + h) * 56 + 4 * f);
    unsigned int pk;
    pk  = (unsigned int)((int)fminf(127.f, fmaxf(-127.f, rintf(v.x / sx))) & 255);
    pk |= ((unsigned int)((int)fminf(127.f, fmaxf(-127.f, rintf(v.y / sx))) & 255)) << 8;
    pk |= ((unsigned int)((int)fminf(127.f, fmaxf(-127.f, rintf(v.z / sx))) & 255)) << 16;
    pk |= ((unsigned int)((int)fminf(127.f, fmaxf(-127.f, rintf(v.w / sx))) & 255)) << 24;
    *(unsigned int*)(ldsA + c * 60 + 4 * f) = pk;
  }
  __syncthreads();
  unsigned int* orow = qxp + (size_t)row * 56 * 32;
  for (int i = threadIdx.x; i < 1792; i += 256) {
    const int w = i >> 5, jd = i & 31;
    // byte p of row w holds channel p ^ (((w+1)&15)<<3); dword-level: ph<<1
    const int c0 = (jd ^ (((w + 1) & 15) << 1)) << 2;  // channel base (4-run)
    unsigned int pk = 0;
#pragma unroll
    for (int k = 0; k < 4; ++k)
      pk |= ((unsigned int)(unsigned char)ldsA[(c0 + k) * 60 + w]) << (8 * k);
    orow[i] = pk;
  }
}

// ---------------- kernel 3: conv (i8 MFMA, 2 output rows per block) --------
#define XSLAB 8448                  // 66 cols * 128B, contiguous (no pad)

__global__ __launch_bounds__(256, 4) void conv_kernel(
    const char* __restrict__ qxp, const char* __restrict__ qwf,
    const float* __restrict__ alpha, const float* __restrict__ bias,
    float* __restrict__ out) {
  __shared__ __attribute__((aligned(16))) char Xs8[4 * XSLAB];  // 33,792 B

  // chunked XCD swizzle: 1792 = 8*224; XCD owns bi2 in [xcd*112,+112), both y
  const int id = blockIdx.x;        // 0..1791
  const int xcd = id & 7;
  int kk = id >> 3;                 // 0..223
  const int yy = (kk >= 112) ? 1 : 0;
  kk -= yy * 112;                   // 0..111
  const int bi2 = xcd * 112 + kk;   // 0..895
  const int b  = bi2 / 28;
  const int oh0 = (bi2 % 28) * 2;   // even; block covers oh0, oh0+1
  const int o0 = yy * 128;
  const int tid = threadIdx.x;
  const int wave = tid >> 6, lane = tid & 63;
  const int l16 = lane & 15, quad = lane >> 4;

  // A-operand base: per-lane long2 (t=0,t=1 fragments), wave chunk = 1KB.
  const longx2* wb2 = (const longx2*)(qwf + (size_t)(yy * 4 + wave) * 36864) +
                      (l16 * 4 + quad);

  // ---- stage 4 input rows ih = oh0-1 .. oh0+2 (serve both output rows) ----
  for (int s = 0; s < 4; ++s) {
    const int ih = oh0 - 1 + s;
    char* slab = Xs8 + s * XSLAB;
    if (ih >= 0 && ih < HH) {
      const char* src = qxp + ((size_t)b * 56 + ih) * 7168;
      for (int i = tid; i < 448; i += 256)
        gload_lds16(src + i * 16, slab + 128 + i * 16);   // cols 1..56
      for (int i = tid; i < 320; i += 256) {              // zero cols 0,57..65
        const int cg = i >> 5, dw = i & 31;
        const int col = (cg == 0) ? 0 : 56 + cg;
        ((unsigned int*)slab)[col * 32 + dw] = 0u;
      }
    } else {
      for (int i = tid; i < 2112; i += 256) ((unsigned int*)slab)[i] = 0u;
    }
  }

  int4v acc[2][2][4];               // [p = oh sub-row][t][u]  (64 VGPR)
#pragma unroll
  for (int p = 0; p < 2; ++p)
#pragma unroll
    for (int t = 0; t < 2; ++t)
#pragma unroll
      for (int u = 0; u < 4; ++u) acc[p][t][u] = (int4v){0, 0, 0, 0};

  __syncthreads();   // drains vmcnt (global_load_lds) + lgkm (zero stores)

  // ---- K-loop: 9 taps x 4 c04; 16 MFMA per substep; short-lived ap/bop ----
  // Output row p at tap kh reads slab kh+p (row overlap reuse).
#pragma unroll
  for (int g = 0; g < 9; ++g) {
    const int kh = g / 3, kw = g % 3;
    const int ph = ((l16 + kw) & 15) << 3;  // 4-bit row-phase, u-invariant
    longx2 ap[4];                           // this tap's A (8 VGPR, JIT)
#pragma unroll
    for (int cc = 0; cc < 4; ++cc) ap[cc] = wb2[(size_t)(g * 4 + cc) * 64];
#pragma unroll
    for (int c04 = 0; c04 < 4; ++c04) {
      const int boff = (c04 * 32 + quad * 8) ^ ph;
      long bop[2][4];                       // current substep only (16 VGPR)
#pragma unroll
      for (int p = 0; p < 2; ++p)
#pragma unroll
        for (int u = 0; u < 4; ++u)
          bop[p][u] = *(const long*)(Xs8 + (kh + p) * XSLAB +
                                     (u * 16 + l16 + kw) * 128 + boff);
#pragma unroll
      for (int p = 0; p < 2; ++p)
#pragma unroll
        for (int u = 0; u < 4; ++u) {
          acc[p][0][u] = __builtin_amdgcn_mfma_i32_16x16x32_i8(
              ap[c04][0], bop[p][u], acc[p][0][u], 0, 0, 0);
          acc[p][1][u] = __builtin_amdgcn_mfma_i32_16x16x32_i8(
              ap[c04][1], bop[p][u], acc[p][1][u], 0, 0, 0);
        }
    }
  }

  // C/D layout (HW-verified, R12-correctness-proven): row=quad*4+r, col=l16
#pragma unroll
  for (int t = 0; t < 2; ++t) {
#pragma unroll
    for (int r = 0; r < 4; ++r) {
      const int o = o0 + wave * 32 + t * 16 + quad * 4 + r;
      const float al = alpha[o], bz = bias[o];
#pragma unroll
      for (int p = 0; p < 2; ++p) {
        float* orow = out + (((size_t)b * OCH + o) * HH + oh0 + p) * WW;
#pragma unroll
        for (int u = 0; u < 4; ++u) {
          const int ow = u * 16 + l16;
          if (ow < WW) orow[ow] = (float)acc[p][t][u][r] * al + bz;
        }
      }
    }
  }
}

// ---------------- fallback: R5's proven fused kernel (ws-free) -------------
#define FAS_ROW 392
#define FXS_ROW 136
#define FLDS_XS (128 * FAS_ROW)
#define FLDS_SC (FLDS_XS + 66 * FXS_ROW)
#define FLDS_AL (FLDS_SC + 512)
#define FLDS_BI (FLDS_AL + 512)
#define FLDS_RED (FLDS_BI + 512)
#define FLDS_TOT (FLDS_RED + 1024)

__global__ __launch_bounds__(256) void conv_fused_kernel(
    const float* __restrict__ x, const float* __restrict__ w,
    const float* __restrict__ bias, const float* __restrict__ sxp,
    float* __restrict__ out) {
  __shared__ __attribute__((aligned(16))) char lds[FLDS_TOT];
  char* As8 = lds;
  char* Xs8 = lds + FLDS_XS;
  float* scaleS = (float*)(lds + FLDS_SC);
  float* alphaS = (float*)(lds + FLDS_AL);
  float* biasS  = (float*)(lds + FLDS_BI);
  float* red    = (float*)(lds + FLDS_RED);

  const int bi = blockIdx.x;
  const int b  = bi / 56;
  const int oh = bi % 56;
  const int o0 = blockIdx.y * 128;
  const int tid = threadIdx.x;
  const int wave = tid >> 6, lane = tid & 63;
  const int l16 = lane & 15, quad = lane >> 4;
  const float sx = sxp[0];

  int m_r[4], n_r[4];
  {
    int4v zz = {0, 0, 0, 0};
    long a1 = 0, b1 = 0, a2 = 0, b2 = 0;
    if (quad == 0) { a1 = 1L; b1 = (long)(l16 + 1); a2 = (long)(l16 + 1); b2 = 1L; }
    int4v d1 = __builtin_amdgcn_mfma_i32_16x16x32_i8(a1, b1, zz, 0, 0, 0);
    int4v d2 = __builtin_amdgcn_mfma_i32_16x16x32_i8(a2, b2, zz, 0, 0, 0);
#pragma unroll
    for (int r = 0; r < 4; ++r) { n_r[r] = (d1[r] - 1) & 15; m_r[r] = (d2[r] - 1) & 15; }
  }
  {
    const int o = tid >> 1, half = tid & 1;
    const float4* p = (const float4*)(w + (size_t)(o0 + o) * 1152 + half * 576);
    float m = 0.f;
#pragma unroll 4
    for (int i = 0; i < 144; ++i) {
      const float4 v = p[i];
      m = fmaxf(m, fmaxf(fmaxf(fabsf(v.x), fabsf(v.y)), fmaxf(fabsf(v.z), fabsf(v.w))));
    }
    red[tid] = m;
  }
  __syncthreads();
  {
    const int o = tid >> 1;
    if ((tid & 1) == 0) {
      const float sc = fmaxf(red[2 * o], red[2 * o + 1]) / 127.0f;
      scaleS[o] = sc; alphaS[o] = sc * sx; biasS[o] = bias[o0 + o];
    }
  }
  int4v acc[2][4];
#pragma unroll
  for (int t = 0; t < 2; ++t)
#pragma unroll
    for (int u = 0; u < 4; ++u) acc[t][u] = (int4v){0, 0, 0, 0};

  for (int kh = 0; kh < 3; ++kh) {
    const int ih = oh - 1 + kh;
    const bool row_ok = (ih >= 0) && (ih < HH);
    __syncthreads();
    for (int idx = tid; idx < 66 * 128; idx += 256) {
      const int col = idx % 66, c = idx / 66, iw = col - 1;
      int q = 0;
      if (row_ok && iw >= 0 && iw < WW) {
        const float xv = x[(((size_t)b * CIN + c) * HH + ih) * WW + iw];
        q = (int)fminf(127.f, fmaxf(-127.f, rintf(xv / sx)));
      }
      Xs8[col * FXS_ROW + c] = (char)q;
    }
    for (int idx = tid; idx < 16384; idx += 256) {
      const int c = idx & 127, o = idx >> 7;
      const float s = scaleS[o];
      const float* wp = w + (size_t)(o0 + o) * 1152 + c * 9 + kh * 3;
#pragma unroll
      for (int kw = 0; kw < 3; ++kw) {
        const int q = (int)fminf(127.f, fmaxf(-127.f, rintf(wp[kw] / s)));
        As8[o * FAS_ROW + kw * 128 + c] = (char)q;
      }
    }
    __syncthreads();
    const int obase = wave * 32;
#pragma unroll
    for (int kw = 0; kw < 3; ++kw) {
#pragma unroll
      for (int c0 = 0; c0 < 128; c0 += 32) {
        long aop[2], bop[4];
#pragma unroll
        for (int t = 0; t < 2; ++t)
          aop[t] = *(const long*)(As8 + (obase + t * 16 + l16) * FAS_ROW + kw * 128 + c0 + quad * 8);
#pragma unroll
        for (int u = 0; u < 4; ++u)
          bop[u] = *(const long*)(Xs8 + (u * 16 + l16 + kw) * FXS_ROW + c0 + quad * 8);
#pragma unroll
        for (int t = 0; t < 2; ++t)
#pragma unroll
          for (int u = 0; u < 4; ++u)
            acc[t][u] = __builtin_amdgcn_mfma_i32_16x16x32_i8(aop[t], bop[u], acc[t][u], 0, 0, 0);
      }
    }
  }
#pragma unroll
  for (int t = 0; t < 2; ++t) {
#pragma unroll
    for (int u = 0; u < 4; ++u) {
#pragma unroll
      for (int r = 0; r < 4; ++r) {
        const int ol = wave * 32 + t * 16 + m_r[r];
        const int ow = u * 16 + n_r[r];
        if (ow < WW)
          out[(((size_t)b * OCH + o0 + ol) * HH + oh) * WW + ow] =
              (float)acc[t][u][r] * alphaS[ol] + biasS[ol];
      }
    }
  }
}

extern "C" void kernel_launch(void* const* d_in, const int* in_sizes, int n_in,
                              void* d_out, int out_size, void* d_ws, size_t ws_size,
                              hipStream_t stream) {
  const float *x = nullptr, *w = nullptr, *bias = nullptr, *sx = nullptr;
  for (int i = 0; i < n_in; ++i) {
    const int s = in_sizes[i];
    if (s == BATCH * CIN * HH * WW) x = (const float*)d_in[i];
    else if (s == OCH * CIN * 9)    w = (const float*)d_in[i];
    else if (s == OCH)              bias = (const float*)d_in[i];
    else if (s == 1)                sx = (const float*)d_in[i];
  }
  if (!x || !w || !bias || !sx) {
    x = (const float*)d_in[0]; w = (const float*)d_in[1];
    bias = (const float*)d_in[2]; sx = (const float*)d_in[3];
  }
  float* out = (float*)d_out;

  if (ws_size >= (size_t)WS_NEEDED) {
    unsigned int* qxp = (unsigned int*)d_ws;
    char* qwf = (char*)d_ws + QX_BYTES;
    float* alpha = (float*)((char*)d_ws + QX_BYTES + QW_BYTES);
    quant_w_kernel<<<OCH, 256, 0, stream>>>(w, sx, qwf, alpha);
    quant_x_kernel<<<BATCH * HH, 256, 0, stream>>>(x, sx, qxp);
    conv_kernel<<<BATCH * HH, 256, 0, stream>>>(
        (const char*)qxp, qwf, alpha, bias, out);
  } else {
    conv_fused_kernel<<<dim3(BATCH * HH, 2), 256, 0, stream>>>(x, w, bias, sx, out);
  }
}

// Round 9
// 189.677 us; speedup vs baseline: 1.6402x; 1.6402x over previous
//
#include <hip/hip_runtime.h>

// Conv2d + BN int8 quantized, MI355X gfx950. Inputs fp32, output fp32.
// R14: R12/R13 proved acc=64/thread always spills at this occupancy (VGPR=64 +
// 350MB scratch, twice). Constraint locked: acc <= 32/thread. Instead, merge
// the duplicate-staging axis: R11's two y-blocks per (b,oh) stage IDENTICAL
// 3 slabs. Fuse into one 512-thread/8-wave block:
//   - wave w runs R11's proven wave body verbatim with og=w (same addressing)
//   - staging bytes/output halve (3 slabs serve all 256 o): FETCH ~21->~11MB
//   - 8-wave blocks, LDS 25.3KB -> up to 32 waves/CU (2x R11's TLP)
//   - grid 1792 = 8*224 keeps bijective chunked XCD swizzle
// Inner K-loop / quant kernels / swizzle / C-D map unchanged (proven at 61us).
// Host falls back to the proven R5 fused kernel if ws_size is too small.

#define BATCH 32
#define CIN   128
#define HH    56
#define WW    56
#define OCH   256

typedef __attribute__((ext_vector_type(4))) int int4v;
typedef __attribute__((ext_vector_type(2))) long longx2;

#define QX_BYTES (32 * 56 * 56 * 128)           // 12,845,056  qxp[b][h][w][c]
#define QW_BYTES (256 * 1152)                   // 294,912 (fragment-packed)
#define WS_NEEDED (QX_BYTES + QW_BYTES + 1024)

__device__ __forceinline__ void gload_lds16(const void* g, void* l) {
  __builtin_amdgcn_global_load_lds(
      (const __attribute__((address_space(1))) unsigned int*)g,
      (__attribute__((address_space(3))) unsigned int*)l, 16, 0, 0);
}

// ---------------- kernel 1: weight quantization + fragment pack ------------
// One block per output channel o. Layout (t-pair merged into long2):
//   byte ((og*36 + r*4 + c04)*128 + (l16*4+quad)*2 + t)*8 + (half*4+k)
//   holds channel c04*32+quad*8+half*4+k of o = og*32+t*16+l16 at tap r.
// Conv lane (l16,quad) of wave og loads long2 at longx2 index
//   og*4608 + (r*4+c04)*64 + l16*4+quad; wave chunk = contiguous 1KB.
__global__ __launch_bounds__(256) void quant_w_kernel(
    const float* __restrict__ w, const float* __restrict__ sxp,
    char* __restrict__ qwf, float* __restrict__ alpha) {
  __shared__ float wf[1152];
  __shared__ float red[256];
  const int o = blockIdx.x;
  const int tid = threadIdx.x;
  const float* wrow = w + (size_t)o * 1152;
  float m = 0.f;
  for (int i = tid; i < 288; i += 256) {
    const float4 v = ((const float4*)wrow)[i];
    ((float4*)wf)[i] = v;
    m = fmaxf(m, fmaxf(fmaxf(fabsf(v.x), fabsf(v.y)),
                       fmaxf(fabsf(v.z), fabsf(v.w))));
  }
  red[tid] = m;
  __syncthreads();
  for (int s = 128; s > 0; s >>= 1) {
    if (tid < s) red[tid] = fmaxf(red[tid], red[tid + s]);
    __syncthreads();
  }
  const float sc = red[0] / 127.0f;   // max/QMAX, fp32, matches reference
  if (tid == 0) alpha[o] = sc * sxp[0];
  if (tid < 36) {
    const int r = tid >> 2, c04 = tid & 3;
    const int og = o >> 5, t = (o >> 4) & 1, l16 = o & 15;
    unsigned int* base = (unsigned int*)(qwf + (size_t)og * 36864 +
                                         (size_t)(r * 4 + c04) * 1024);
#pragma unroll
    for (int quad = 0; quad < 4; ++quad) {
#pragma unroll
      for (int half = 0; half < 2; ++half) {
        unsigned int pk = 0;
#pragma unroll
        for (int k = 0; k < 4; ++k) {
          const int c = c04 * 32 + quad * 8 + half * 4 + k;
          const int q =
              (int)fminf(127.f, fmaxf(-127.f, rintf(wf[c * 9 + r] / sc)));
          pk |= ((unsigned int)(q & 255)) << (8 * k);
        }
        base[(l16 * 4 + quad) * 4 + t * 2 + half] = pk;
      }
    }
  }
}

// ---------------- kernel 2: x quantization -> swizzled im2col rows ---------
// qxp byte ((b*56+h)*56 + w)*128 + j holds q(x[b][ j^(((w+1)&15)<<3) ][h][w]).
__global__ __launch_bounds__(256) void quant_x_kernel(
    const float* __restrict__ x, const float* __restrict__ sxp,
    unsigned int* __restrict__ qxp) {
  __shared__ char ldsA[128 * 60];   // [c][w] quantized bytes, stride 60
  const int row = blockIdx.x;       // b*56 + h
  const int b = row / 56, h = row % 56;
  const float sx = sxp[0];
  for (int i = threadIdx.x; i < 1792; i += 256) {
    const int c = i / 14, f = i % 14;
    const float4 v =
        *(const float4*)(x + (((size_t)b * 128 + c) * 56 + h) * 56 + 4 * f);
    unsigned int pk;
    pk  = (unsigned int)((int)fminf(127.f, fmaxf(-127.f, rintf(v.x / sx))) & 255);
    pk |= ((unsigned int)((int)fminf(127.f, fmaxf(-127.f, rintf(v.y / sx))) & 255)) << 8;
    pk |= ((unsigned int)((int)fminf(127.f, fmaxf(-127.f, rintf(v.z / sx))) & 255)) << 16;
    pk |= ((unsigned int)((int)fminf(127.f, fmaxf(-127.f, rintf(v.w / sx))) & 255)) << 24;
    *(unsigned int*)(ldsA + c * 60 + 4 * f) = pk;
  }
  __syncthreads();
  unsigned int* orow = qxp + (size_t)row * 56 * 32;
  for (int i = threadIdx.x; i < 1792; i += 256) {
    const int w = i >> 5, jd = i & 31;
    // byte p of row w holds channel p ^ (((w+1)&15)<<3); dword-level: ph<<1
    const int c0 = (jd ^ (((w + 1) & 15) << 1)) << 2;  // channel base (4-run)
    unsigned int pk = 0;
#pragma unroll
    for (int k = 0; k < 4; ++k)
      pk |= ((unsigned int)(unsigned char)ldsA[(c0 + k) * 60 + w]) << (8 * k);
    orow[i] = pk;
  }
}

// ---------------- kernel 3: conv (i8 MFMA, 8 waves, all 256 o per block) ---
#define XSLAB 8448                  // 66 cols * 128B, contiguous (no pad)

__global__ __launch_bounds__(512, 4) void conv_kernel(
    const char* __restrict__ qxp, const char* __restrict__ qwf,
    const float* __restrict__ alpha, const float* __restrict__ bias,
    float* __restrict__ out) {
  __shared__ __attribute__((aligned(16))) char Xs8[3 * XSLAB];  // 25,344 B

  // chunked XCD swizzle: 1792 = 8*224; XCD (id&7) owns bi in [xcd*224,+224)
  const int id = blockIdx.x;        // 0..1791
  const int xcd = id & 7;
  const int bi = xcd * 224 + (id >> 3);
  const int b  = bi / 56;
  const int oh = bi % 56;
  const int tid = threadIdx.x;      // 0..511
  const int wave = tid >> 6, lane = tid & 63;   // wave = og, 0..7
  const int l16 = lane & 15, quad = lane >> 4;

  // A-operand base: per-lane long2 (t=0,t=1 fragments), wave chunk = 1KB.
  const longx2* wb2 = (const longx2*)(qwf + (size_t)wave * 36864) +
                      (l16 * 4 + quad);
  longx2 ap[2][4];
#pragma unroll
  for (int c04 = 0; c04 < 4; ++c04) ap[0][c04] = wb2[(size_t)c04 * 64];

  // ---- stage 3 input rows once for ALL 256 o (512 threads) ----
  for (int kh = 0; kh < 3; ++kh) {
    const int ih = oh - 1 + kh;
    char* slab = Xs8 + kh * XSLAB;
    if (ih >= 0 && ih < HH) {
      const char* src = qxp + ((size_t)b * 56 + ih) * 7168;
      if (tid < 448) gload_lds16(src + tid * 16, slab + 128 + tid * 16);
      for (int i = tid; i < 320; i += 512) {              // zero cols 0,57..65
        const int cg = i >> 5, dw = i & 31;
        const int col = (cg == 0) ? 0 : 56 + cg;
        ((unsigned int*)slab)[col * 32 + dw] = 0u;
      }
    } else {
      for (int i = tid; i < 2112; i += 512) ((unsigned int*)slab)[i] = 0u;
    }
  }

  int4v acc[2][4];
#pragma unroll
  for (int t = 0; t < 2; ++t)
#pragma unroll
    for (int u = 0; u < 4; ++u) acc[t][u] = (int4v){0, 0, 0, 0};

  __syncthreads();   // drains vmcnt (global_load_lds + ap[0]) + lgkm

  // ---- K-loop: 36 steps (9 taps x 4 c04), B ping-ponged one step ahead ----
  long bops[2][4];
  {
    const int ph0 = (l16 & 15) << 3;        // g=0: kh=0, kw=0
    const int boff0 = (quad * 8) ^ ph0;     // c04=0
#pragma unroll
    for (int u = 0; u < 4; ++u)
      bops[0][u] = *(const long*)(Xs8 + (u * 16 + l16) * 128 + boff0);
  }
#pragma unroll
  for (int step = 0; step < 36; ++step) {
    const int g = step >> 2, c04 = step & 3;
    // prefetch next step's B fragments (static after unroll)
    if (step + 1 < 36) {
      const int gn = (step + 1) >> 2, cn = (step + 1) & 3;
      const int khn = gn / 3, kwn = gn % 3;
      const char* Xkn = Xs8 + khn * XSLAB;
      const int phn = ((l16 + kwn) & 15) << 3;
      const int boffn = (cn * 32 + quad * 8) ^ phn;
#pragma unroll
      for (int u = 0; u < 4; ++u)
        bops[(step + 1) & 1][u] =
            *(const long*)(Xkn + (u * 16 + l16 + kwn) * 128 + boffn);
    }
    // prefetch next tap's A fragments (once per g)
    if (c04 == 0 && g < 8) {
#pragma unroll
      for (int cc = 0; cc < 4; ++cc)
        ap[(g + 1) & 1][cc] = wb2[(size_t)((g + 1) * 4 + cc) * 64];
    }
#pragma unroll
    for (int u = 0; u < 4; ++u) {
      acc[0][u] = __builtin_amdgcn_mfma_i32_16x16x32_i8(
          ap[g & 1][c04][0], bops[step & 1][u], acc[0][u], 0, 0, 0);
      acc[1][u] = __builtin_amdgcn_mfma_i32_16x16x32_i8(
          ap[g & 1][c04][1], bops[step & 1][u], acc[1][u], 0, 0, 0);
    }
  }

  // C/D layout (HW-verified, proven since R12): row = quad*4+r, col = l16
#pragma unroll
  for (int t = 0; t < 2; ++t) {
#pragma unroll
    for (int r = 0; r < 4; ++r) {
      const int o = wave * 32 + t * 16 + quad * 4 + r;
      const float al = alpha[o], bz = bias[o];
      float* orow = out + (((size_t)b * OCH + o) * HH + oh) * WW;
#pragma unroll
      for (int u = 0; u < 4; ++u) {
        const int ow = u * 16 + l16;
        if (ow < WW) orow[ow] = (float)acc[t][u][r] * al + bz;
      }
    }
  }
}

// ---------------- fallback: R5's proven fused kernel (ws-free) -------------
#define FAS_ROW 392
#define FXS_ROW 136
#define FLDS_XS (128 * FAS_ROW)
#define FLDS_SC (FLDS_XS + 66 * FXS_ROW)
#define FLDS_AL (FLDS_SC + 512)
#define FLDS_BI (FLDS_AL + 512)
#define FLDS_RED (FLDS_BI + 512)
#define FLDS_TOT (FLDS_RED + 1024)

__global__ __launch_bounds__(256) void conv_fused_kernel(
    const float* __restrict__ x, const float* __restrict__ w,
    const float* __restrict__ bias, const float* __restrict__ sxp,
    float* __restrict__ out) {
  __shared__ __attribute__((aligned(16))) char lds[FLDS_TOT];
  char* As8 = lds;
  char* Xs8 = lds + FLDS_XS;
  float* scaleS = (float*)(lds + FLDS_SC);
  float* alphaS = (float*)(lds + FLDS_AL);
  float* biasS  = (float*)(lds + FLDS_BI);
  float* red    = (float*)(lds + FLDS_RED);

  const int bi = blockIdx.x;
  const int b  = bi / 56;
  const int oh = bi % 56;
  const int o0 = blockIdx.y * 128;
  const int tid = threadIdx.x;
  const int wave = tid >> 6, lane = tid & 63;
  const int l16 = lane & 15, quad = lane >> 4;
  const float sx = sxp[0];

  int m_r[4], n_r[4];
  {
    int4v zz = {0, 0, 0, 0};
    long a1 = 0, b1 = 0, a2 = 0, b2 = 0;
    if (quad == 0) { a1 = 1L; b1 = (long)(l16 + 1); a2 = (long)(l16 + 1); b2 = 1L; }
    int4v d1 = __builtin_amdgcn_mfma_i32_16x16x32_i8(a1, b1, zz, 0, 0, 0);
    int4v d2 = __builtin_amdgcn_mfma_i32_16x16x32_i8(a2, b2, zz, 0, 0, 0);
#pragma unroll
    for (int r = 0; r < 4; ++r) { n_r[r] = (d1[r] - 1) & 15; m_r[r] = (d2[r] - 1) & 15; }
  }
  {
    const int o = tid >> 1, half = tid & 1;
    const float4* p = (const float4*)(w + (size_t)(o0 + o) * 1152 + half * 576);
    float m = 0.f;
#pragma unroll 4
    for (int i = 0; i < 144; ++i) {
      const float4 v = p[i];
      m = fmaxf(m, fmaxf(fmaxf(fabsf(v.x), fabsf(v.y)), fmaxf(fabsf(v.z), fabsf(v.w))));
    }
    red[tid] = m;
  }
  __syncthreads();
  {
    const int o = tid >> 1;
    if ((tid & 1) == 0) {
      const float sc = fmaxf(red[2 * o], red[2 * o + 1]) / 127.0f;
      scaleS[o] = sc; alphaS[o] = sc * sx; biasS[o] = bias[o0 + o];
    }
  }
  int4v acc[2][4];
#pragma unroll
  for (int t = 0; t < 2; ++t)
#pragma unroll
    for (int u = 0; u < 4; ++u) acc[t][u] = (int4v){0, 0, 0, 0};

  for (int kh = 0; kh < 3; ++kh) {
    const int ih = oh - 1 + kh;
    const bool row_ok = (ih >= 0) && (ih < HH);
    __syncthreads();
    for (int idx = tid; idx < 66 * 128; idx += 256) {
      const int col = idx % 66, c = idx / 66, iw = col - 1;
      int q = 0;
      if (row_ok && iw >= 0 && iw < WW) {
        const float xv = x[(((size_t)b * CIN + c) * HH + ih) * WW + iw];
        q = (int)fminf(127.f, fmaxf(-127.f, rintf(xv / sx)));
      }
      Xs8[col * FXS_ROW + c] = (char)q;
    }
    for (int idx = tid; idx < 16384; idx += 256) {
      const int c = idx & 127, o = idx >> 7;
      const float s = scaleS[o];
      const float* wp = w + (size_t)(o0 + o) * 1152 + c * 9 + kh * 3;
#pragma unroll
      for (int kw = 0; kw < 3; ++kw) {
        const int q = (int)fminf(127.f, fmaxf(-127.f, rintf(wp[kw] / s)));
        As8[o * FAS_ROW + kw * 128 + c] = (char)q;
      }
    }
    __syncthreads();
    const int obase = wave * 32;
#pragma unroll
    for (int kw = 0; kw < 3; ++kw) {
#pragma unroll
      for (int c0 = 0; c0 < 128; c0 += 32) {
        long aop[2], bop[4];
#pragma unroll
        for (int t = 0; t < 2; ++t)
          aop[t] = *(const long*)(As8 + (obase + t * 16 + l16) * FAS_ROW + kw * 128 + c0 + quad * 8);
#pragma unroll
        for (int u = 0; u < 4; ++u)
          bop[u] = *(const long*)(Xs8 + (u * 16 + l16 + kw) * FXS_ROW + c0 + quad * 8);
#pragma unroll
        for (int t = 0; t < 2; ++t)
#pragma unroll
          for (int u = 0; u < 4; ++u)
            acc[t][u] = __builtin_amdgcn_mfma_i32_16x16x32_i8(aop[t], bop[u], acc[t][u], 0, 0, 0);
      }
    }
  }
#pragma unroll
  for (int t = 0; t < 2; ++t) {
#pragma unroll
    for (int u = 0; u < 4; ++u) {
#pragma unroll
      for (int r = 0; r < 4; ++r) {
        const int ol = wave * 32 + t * 16 + m_r[r];
        const int ow = u * 16 + n_r[r];
        if (ow < WW)
          out[(((size_t)b * OCH + o0 + ol) * HH + oh) * WW + ow] =
              (float)acc[t][u][r] * alphaS[ol] + biasS[ol];
      }
    }
  }
}

extern "C" void kernel_launch(void* const* d_in, const int* in_sizes, int n_in,
                              void* d_out, int out_size, void* d_ws, size_t ws_size,
                              hipStream_t stream) {
  const float *x = nullptr, *w = nullptr, *bias = nullptr, *sx = nullptr;
  for (int i = 0; i < n_in; ++i) {
    const int s = in_sizes[i];
    if (s == BATCH * CIN * HH * WW) x = (const float*)d_in[i];
    else if (s == OCH * CIN * 9)    w = (const float*)d_in[i];
    else if (s == OCH)              bias = (const float*)d_in[i];
    else if (s == 1)                sx = (const float*)d_in[i];
  }
  if (!x || !w || !bias || !sx) {
    x = (const float*)d_in[0]; w = (const float*)d_in[1];
    bias = (const float*)d_in[2]; sx = (const float*)d_in[3];
  }
  float* out = (float*)d_out;

  if (ws_size >= (size_t)WS_NEEDED) {
    unsigned int* qxp = (unsigned int*)d_ws;
    char* qwf = (char*)d_ws + QX_BYTES;
    float* alpha = (float*)((char*)d_ws + QX_BYTES + QW_BYTES);
    quant_w_kernel<<<OCH, 256, 0, stream>>>(w, sx, qwf, alpha);
    quant_x_kernel<<<BATCH * HH, 256, 0, stream>>>(x, sx, qxp);
    conv_kernel<<<BATCH * HH, 512, 0, stream>>>(
        (const char*)qxp, qwf, alpha, bias, out);
  } else {
    conv_fused_kernel<<<dim3(BATCH * HH, 2), 256, 0, stream>>>(x, w, bias, sx, out);
  }
}

// Round 11
// 185.216 us; speedup vs baseline: 1.6797x; 1.0241x over previous
//
#include <hip/hip_runtime.h>

// Conv2d + BN int8 quantized, MI355X gfx950. Inputs fp32, output fp32.
// R16: R15 failed correctness from a LANE-PERMUTATION bug (not the MFMA
// layout): conv reads A at wbA+lane (lane = quad*16+l16, HW order) but
// quant_w wrote lane (l16,quad)'s fragment at l16*4+quad (stale R9 ordering).
// Fix: quant_w writes at (quad*16+l16)*16. All else identical to R15:
//   - mfma_i32_16x16x64_i8: MFMA instrs/wave 288->144, LDS b128 issues halved
//   - A layout m=l16, k=quad*16+e (family pattern); C/D map shape-determined
//   - qxp swizzle 3bit/16B (ph=((w+1)&7)<<4), re-derived invariant & bijective
//   - R11-proven 256-thr block, A-pp per tap + B-pp per substep, bounds(256,4)
// Host falls back to the proven R5 fused kernel if ws_size is too small.

#define BATCH 32
#define CIN   128
#define HH    56
#define WW    56
#define OCH   256

typedef __attribute__((ext_vector_type(4))) int int4v;

#define QX_BYTES (32 * 56 * 56 * 128)           // 12,845,056  qxp[b][h][w][c]
#define QW_BYTES (256 * 1152)                   // 294,912 (fragment-packed)
#define WS_NEEDED (QX_BYTES + QW_BYTES + 1024)

__device__ __forceinline__ void gload_lds16(const void* g, void* l) {
  __builtin_amdgcn_global_load_lds(
      (const __attribute__((address_space(1))) unsigned int*)g,
      (__attribute__((address_space(3))) unsigned int*)l, 16, 0, 0);
}

// ---------------- kernel 1: weight quantization + fragment pack ------------
// One block per output channel o. A-fragment layout for 16x16x64 i8:
//   int4v at qwf + og*36864 + ((r*2+c02)*2+t)*1024 + (quad*16+l16)*16
//   (= lane*16, lane = quad*16+l16, HW order): byte e holds channel
//   c02*64 + quad*16 + e of o = og*32+t*16+l16 at tap r = kh*3+kw.
//   Wave chunk per (r,c02,t) = contiguous 1KB.
__global__ __launch_bounds__(256) void quant_w_kernel(
    const float* __restrict__ w, const float* __restrict__ sxp,
    char* __restrict__ qwf, float* __restrict__ alpha) {
  __shared__ float wf[1152];
  __shared__ float red[256];
  const int o = blockIdx.x;
  const int tid = threadIdx.x;
  const float* wrow = w + (size_t)o * 1152;
  float m = 0.f;
  for (int i = tid; i < 288; i += 256) {
    const float4 v = ((const float4*)wrow)[i];
    ((float4*)wf)[i] = v;
    m = fmaxf(m, fmaxf(fmaxf(fabsf(v.x), fabsf(v.y)),
                       fmaxf(fabsf(v.z), fabsf(v.w))));
  }
  red[tid] = m;
  __syncthreads();
  for (int s = 128; s > 0; s >>= 1) {
    if (tid < s) red[tid] = fmaxf(red[tid], red[tid + s]);
    __syncthreads();
  }
  const float sc = red[0] / 127.0f;   // max/QMAX, fp32, matches reference
  if (tid == 0) alpha[o] = sc * sxp[0];
  if (tid < 72) {   // r = tid/8, c02 = (tid>>2)&1, quad = tid&3
    const int r = tid >> 3, c02 = (tid >> 2) & 1, quad = tid & 3;
    const int og = o >> 5, t = (o >> 4) & 1, l16 = o & 15;
    int4v pk;
#pragma unroll
    for (int d = 0; d < 4; ++d) {
      unsigned int p = 0;
#pragma unroll
      for (int k = 0; k < 4; ++k) {
        const int c = c02 * 64 + quad * 16 + d * 4 + k;
        const int q =
            (int)fminf(127.f, fmaxf(-127.f, rintf(wf[c * 9 + r] / sc)));
        p |= ((unsigned int)(q & 255)) << (8 * k);
      }
      pk[d] = (int)p;
    }
    *(int4v*)(qwf + (size_t)og * 36864 + ((r * 2 + c02) * 2 + t) * 1024 +
              (quad * 16 + l16) * 16) = pk;   // R16 fix: HW lane order
  }
}

// ---------------- kernel 2: x quantization -> swizzled im2col rows ---------
// qxp byte ((b*56+h)*56 + w)*128 + j holds q(x[b][ j^(((w+1)&7)<<4) ][h][w]).
__global__ __launch_bounds__(256) void quant_x_kernel(
    const float* __restrict__ x, const float* __restrict__ sxp,
    unsigned int* __restrict__ qxp) {
  __shared__ char ldsA[128 * 60];   // [c][w] quantized bytes, stride 60
  const int row = blockIdx.x;       // b*56 + h
  const int b = row / 56, h = row % 56;
  const float sx = sxp[0];
  for (int i = threadIdx.x; i < 1792; i += 256) {
    const int c = i / 14, f = i % 14;
    const float4 v =
        *(const float4*)(x + (((size_t)b * 128 + c) * 56 + h) * 56 + 4 * f);
    unsigned int pk;
    pk  = (unsigned int)((int)fminf(127.f, fmaxf(-127.f, rintf(v.x / sx))) & 255);
    pk |= ((unsigned int)((int)fminf(127.f, fmaxf(-127.f, rintf(v.y / sx))) & 255)) << 8;
    pk |= ((unsigned int)((int)fminf(127.f, fmaxf(-127.f, rintf(v.z / sx))) & 255)) << 16;
    pk |= ((unsigned int)((int)fminf(127.f, fmaxf(-127.f, rintf(v.w / sx))) & 255)) << 24;
    *(unsigned int*)(ldsA + c * 60 + 4 * f) = pk;
  }
  __syncthreads();
  unsigned int* orow = qxp + (size_t)row * 56 * 32;
  for (int i = threadIdx.x; i < 1792; i += 256) {
    const int w = i >> 5, jd = i & 31;
    // byte p of row w holds channel p ^ (((w+1)&7)<<4); dword-level: ph<<2
    const int c0 = (jd ^ (((w + 1) & 7) << 2)) << 2;  // channel base (4-run)
    unsigned int pk = 0;
#pragma unroll
    for (int k = 0; k < 4; ++k)
      pk |= ((unsigned int)(unsigned char)ldsA[(c0 + k) * 60 + w]) << (8 * k);
    orow[i] = pk;
  }
}

// ---------------- kernel 3: conv (16x16x64 i8 MFMA, weights from L2) -------
#define XSLAB 8448                  // 66 cols * 128B, contiguous (no pad)

__global__ __launch_bounds__(256, 4) void conv_kernel(
    const char* __restrict__ qxp, const char* __restrict__ qwf,
    const float* __restrict__ alpha, const float* __restrict__ bias,
    float* __restrict__ out) {
  __shared__ __attribute__((aligned(16))) char Xs8[3 * XSLAB];  // 25,344 B

  // chunked XCD swizzle: XCD (id&7) owns bi in [xcd*224, xcd*224+224), both y
  const int id = blockIdx.x;        // 0..3583, grid is 1-D
  const int xcd = id & 7;
  int kk = id >> 3;                 // 0..447
  const int yy = (kk >= 224) ? 1 : 0;
  kk -= yy * 224;                   // 0..223
  const int bi = xcd * 224 + kk;
  const int b  = bi / 56;
  const int oh = bi % 56;
  const int o0 = yy * 128;
  const int tid = threadIdx.x;
  const int wave = tid >> 6, lane = tid & 63;
  const int l16 = lane & 15, quad = lane >> 4;

  // A-operand base: per-lane int4v (16B); wave chunk per (r,c02,t) = 1KB.
  const int4v* wbA =
      (const int4v*)(qwf + (size_t)(yy * 4 + wave) * 36864) + lane;
  int4v ap[2][2][2];                // [buf][c02][t]
#pragma unroll
  for (int c02 = 0; c02 < 2; ++c02)
#pragma unroll
    for (int t = 0; t < 2; ++t)
      ap[0][c02][t] = wbA[(size_t)(c02 * 2 + t) * 64];   // r = 0

  // ---- stage 3 input rows: contiguous async copies + small zero fills ----
  for (int kh = 0; kh < 3; ++kh) {
    const int ih = oh - 1 + kh;
    char* slab = Xs8 + kh * XSLAB;
    if (ih >= 0 && ih < HH) {
      const char* src = qxp + ((size_t)b * 56 + ih) * 7168;
      for (int i = tid; i < 448; i += 256)
        gload_lds16(src + i * 16, slab + 128 + i * 16);   // cols 1..56
      for (int i = tid; i < 320; i += 256) {              // zero cols 0,57..65
        const int cg = i >> 5, dw = i & 31;
        const int col = (cg == 0) ? 0 : 56 + cg;
        ((unsigned int*)slab)[col * 32 + dw] = 0u;
      }
    } else {
      for (int i = tid; i < 2112; i += 256) ((unsigned int*)slab)[i] = 0u;
    }
  }

  int4v acc[2][4];
#pragma unroll
  for (int t = 0; t < 2; ++t)
#pragma unroll
    for (int u = 0; u < 4; ++u) acc[t][u] = (int4v){0, 0, 0, 0};

  __syncthreads();   // drains vmcnt (global_load_lds + ap[0]) + lgkm

  // ---- K-loop: 18 substeps (9 taps x 2 K64-chunks), B-pp, A-pp per tap ----
  int4v bops[2][4];
  {
    const int ph0 = (l16 & 7) << 4;         // g=0: kh=0, kw=0
    const int boff0 = (quad * 16) ^ ph0;    // c02=0
#pragma unroll
    for (int u = 0; u < 4; ++u)
      bops[0][u] = *(const int4v*)(Xs8 + (u * 16 + l16) * 128 + boff0);
  }
#pragma unroll
  for (int ss = 0; ss < 18; ++ss) {
    const int g = ss >> 1, c02 = ss & 1;
    // prefetch next substep's B fragments (static after unroll)
    if (ss + 1 < 18) {
      const int gn = (ss + 1) >> 1, cn = (ss + 1) & 1;
      const int khn = gn / 3, kwn = gn % 3;
      const char* Xkn = Xs8 + khn * XSLAB;
      const int phn = ((l16 + kwn) & 7) << 4;
      const int boffn = (cn * 64 + quad * 16) ^ phn;
#pragma unroll
      for (int u = 0; u < 4; ++u)
        bops[(ss + 1) & 1][u] =
            *(const int4v*)(Xkn + (u * 16 + l16 + kwn) * 128 + boffn);
    }
    // prefetch next tap's A fragments (once per g)
    if (c02 == 0 && g < 8) {
#pragma unroll
      for (int cc = 0; cc < 2; ++cc)
#pragma unroll
        for (int t = 0; t < 2; ++t)
          ap[(g + 1) & 1][cc][t] =
              wbA[(size_t)(((g + 1) * 2 + cc) * 2 + t) * 64];
    }
#pragma unroll
    for (int u = 0; u < 4; ++u) {
      acc[0][u] = __builtin_amdgcn_mfma_i32_16x16x64_i8(
          ap[g & 1][c02][0], bops[ss & 1][u], acc[0][u], 0, 0, 0);
      acc[1][u] = __builtin_amdgcn_mfma_i32_16x16x64_i8(
          ap[g & 1][c02][1], bops[ss & 1][u], acc[1][u], 0, 0, 0);
    }
  }

  // C/D layout (HW-verified, proven since R12): row = quad*4+r, col = l16
#pragma unroll
  for (int t = 0; t < 2; ++t) {
#pragma unroll
    for (int r = 0; r < 4; ++r) {
      const int o = o0 + wave * 32 + t * 16 + quad * 4 + r;
      const float al = alpha[o], bz = bias[o];
      float* orow = out + (((size_t)b * OCH + o) * HH + oh) * WW;
#pragma unroll
      for (int u = 0; u < 4; ++u) {
        const int ow = u * 16 + l16;
        if (ow < WW) orow[ow] = (float)acc[t][u][r] * al + bz;
      }
    }
  }
}

// ---------------- fallback: R5's proven fused kernel (ws-free) -------------
#define FAS_ROW 392
#define FXS_ROW 136
#define FLDS_XS (128 * FAS_ROW)
#define FLDS_SC (FLDS_XS + 66 * FXS_ROW)
#define FLDS_AL (FLDS_SC + 512)
#define FLDS_BI (FLDS_AL + 512)
#define FLDS_RED (FLDS_BI + 512)
#define FLDS_TOT (FLDS_RED + 1024)

__global__ __launch_bounds__(256) void conv_fused_kernel(
    const float* __restrict__ x, const float* __restrict__ w,
    const float* __restrict__ bias, const float* __restrict__ sxp,
    float* __restrict__ out) {
  __shared__ __attribute__((aligned(16))) char lds[FLDS_TOT];
  char* As8 = lds;
  char* Xs8 = lds + FLDS_XS;
  float* scaleS = (float*)(lds + FLDS_SC);
  float* alphaS = (float*)(lds + FLDS_AL);
  float* biasS  = (float*)(lds + FLDS_BI);
  float* red    = (float*)(lds + FLDS_RED);

  const int bi = blockIdx.x;
  const int b  = bi / 56;
  const int oh = bi % 56;
  const int o0 = blockIdx.y * 128;
  const int tid = threadIdx.x;
  const int wave = tid >> 6, lane = tid & 63;
  const int l16 = lane & 15, quad = lane >> 4;
  const float sx = sxp[0];

  typedef __attribute__((ext_vector_type(4))) int int4vf;
  int m_r[4], n_r[4];
  {
    int4vf zz = {0, 0, 0, 0};
    long a1 = 0, b1 = 0, a2 = 0, b2 = 0;
    if (quad == 0) { a1 = 1L; b1 = (long)(l16 + 1); a2 = (long)(l16 + 1); b2 = 1L; }
    int4vf d1 = __builtin_amdgcn_mfma_i32_16x16x32_i8(a1, b1, zz, 0, 0, 0);
    int4vf d2 = __builtin_amdgcn_mfma_i32_16x16x32_i8(a2, b2, zz, 0, 0, 0);
#pragma unroll
    for (int r = 0; r < 4; ++r) { n_r[r] = (d1[r] - 1) & 15; m_r[r] = (d2[r] - 1) & 15; }
  }
  {
    const int o = tid >> 1, half = tid & 1;
    const float4* p = (const float4*)(w + (size_t)(o0 + o) * 1152 + half * 576);
    float m = 0.f;
#pragma unroll 4
    for (int i = 0; i < 144; ++i) {
      const float4 v = p[i];
      m = fmaxf(m, fmaxf(fmaxf(fabsf(v.x), fabsf(v.y)), fmaxf(fabsf(v.z), fabsf(v.w))));
    }
    red[tid] = m;
  }
  __syncthreads();
  {
    const int o = tid >> 1;
    if ((tid & 1) == 0) {
      const float sc = fmaxf(red[2 * o], red[2 * o + 1]) / 127.0f;
      scaleS[o] = sc; alphaS[o] = sc * sx; biasS[o] = bias[o0 + o];
    }
  }
  int4vf acc[2][4];
#pragma unroll
  for (int t = 0; t < 2; ++t)
#pragma unroll
    for (int u = 0; u < 4; ++u) acc[t][u] = (int4vf){0, 0, 0, 0};

  for (int kh = 0; kh < 3; ++kh) {
    const int ih = oh - 1 + kh;
    const bool row_ok = (ih >= 0) && (ih < HH);
    __syncthreads();
    for (int idx = tid; idx < 66 * 128; idx += 256) {
      const int col = idx % 66, c = idx / 66, iw = col - 1;
      int q = 0;
      if (row_ok && iw >= 0 && iw < WW) {
        const float xv = x[(((size_t)b * CIN + c) * HH + ih) * WW + iw];
        q = (int)fminf(127.f, fmaxf(-127.f, rintf(xv / sx)));
      }
      Xs8[col * FXS_ROW + c] = (char)q;
    }
    for (int idx = tid; idx < 16384; idx += 256) {
      const int c = idx & 127, o = idx >> 7;
      const float s = scaleS[o];
      const float* wp = w + (size_t)(o0 + o) * 1152 + c * 9 + kh * 3;
#pragma unroll
      for (int kw = 0; kw < 3; ++kw) {
        const int q = (int)fminf(127.f, fmaxf(-127.f, rintf(wp[kw] / s)));
        As8[o * FAS_ROW + kw * 128 + c] = (char)q;
      }
    }
    __syncthreads();
    const int obase = wave * 32;
#pragma unroll
    for (int kw = 0; kw < 3; ++kw) {
#pragma unroll
      for (int c0 = 0; c0 < 128; c0 += 32) {
        long aop[2], bop[4];
#pragma unroll
        for (int t = 0; t < 2; ++t)
          aop[t] = *(const long*)(As8 + (obase + t * 16 + l16) * FAS_ROW + kw * 128 + c0 + quad * 8);
#pragma unroll
        for (int u = 0; u < 4; ++u)
          bop[u] = *(const long*)(Xs8 + (u * 16 + l16 + kw) * FXS_ROW + c0 + quad * 8);
#pragma unroll
        for (int t = 0; t < 2; ++t)
#pragma unroll
          for (int u = 0; u < 4; ++u)
            acc[t][u] = __builtin_amdgcn_mfma_i32_16x16x32_i8(aop[t], bop[u], acc[t][u], 0, 0, 0);
      }
    }
  }
#pragma unroll
  for (int t = 0; t < 2; ++t) {
#pragma unroll
    for (int u = 0; u < 4; ++u) {
#pragma unroll
      for (int r = 0; r < 4; ++r) {
        const int ol = wave * 32 + t * 16 + m_r[r];
        const int ow = u * 16 + n_r[r];
        if (ow < WW)
          out[(((size_t)b * OCH + o0 + ol) * HH + oh) * WW + ow] =
              (float)acc[t][u][r] * alphaS[ol] + biasS[ol];
      }
    }
  }
}

extern "C" void kernel_launch(void* const* d_in, const int* in_sizes, int n_in,
                              void* d_out, int out_size, void* d_ws, size_t ws_size,
                              hipStream_t stream) {
  const float *x = nullptr, *w = nullptr, *bias = nullptr, *sx = nullptr;
  for (int i = 0; i < n_in; ++i) {
    const int s = in_sizes[i];
    if (s == BATCH * CIN * HH * WW) x = (const float*)d_in[i];
    else if (s == OCH * CIN * 9)    w = (const float*)d_in[i];
    else if (s == OCH)              bias = (const float*)d_in[i];
    else if (s == 1)                sx = (const float*)d_in[i];
  }
  if (!x || !w || !bias || !sx) {
    x = (const float*)d_in[0]; w = (const float*)d_in[1];
    bias = (const float*)d_in[2]; sx = (const float*)d_in[3];
  }
  float* out = (float*)d_out;

  if (ws_size >= (size_t)WS_NEEDED) {
    unsigned int* qxp = (unsigned int*)d_ws;
    char* qwf = (char*)d_ws + QX_BYTES;
    float* alpha = (float*)((char*)d_ws + QX_BYTES + QW_BYTES);
    quant_w_kernel<<<OCH, 256, 0, stream>>>(w, sx, qwf, alpha);
    quant_x_kernel<<<BATCH * HH, 256, 0, stream>>>(x, sx, qxp);
    conv_kernel<<<BATCH * HH * 2, 256, 0, stream>>>(
        (const char*)qxp, qwf, alpha, bias, out);
  } else {
    conv_fused_kernel<<<dim3(BATCH * HH, 2), 256, 0, stream>>>(x, w, bias, sx, out);
  }
}

// Round 12
// 181.299 us; speedup vs baseline: 1.7160x; 1.0216x over previous
//
#include <hip/hip_runtime.h>

// Conv2d + BN int8 quantized, MI355X gfx950. Inputs fp32, output fp32.
// R17 = R14 (x) R16, both harness-proven and orthogonal:
//   - R14: 512-thr/8-wave block, wave=og covers all 256 o; 3 slabs staged ONCE
//     per (b,oh) (was 2x by the two y-half blocks) -> FETCH ~21->~11MB
//   - R16: mfma_i32_16x16x64_i8 K-loop (144 MFMA/wave, b128 B-reads, 3bit/16B
//     qxp swizzle, A layout m=l16 k=quad*16+e with HW lane order)
//   regs ~95 < 128 @ bounds(512,4) (16 waves/CU); grid 1792 = 8*224 XCD chunks
// Host falls back to the proven R5 fused kernel if ws_size is too small.

#define BATCH 32
#define CIN   128
#define HH    56
#define WW    56
#define OCH   256

typedef __attribute__((ext_vector_type(4))) int int4v;

#define QX_BYTES (32 * 56 * 56 * 128)           // 12,845,056  qxp[b][h][w][c]
#define QW_BYTES (256 * 1152)                   // 294,912 (fragment-packed)
#define WS_NEEDED (QX_BYTES + QW_BYTES + 1024)

__device__ __forceinline__ void gload_lds16(const void* g, void* l) {
  __builtin_amdgcn_global_load_lds(
      (const __attribute__((address_space(1))) unsigned int*)g,
      (__attribute__((address_space(3))) unsigned int*)l, 16, 0, 0);
}

// ---------------- kernel 1: weight quantization + fragment pack ------------
// One block per output channel o. A-fragment layout for 16x16x64 i8 (R16):
//   int4v at qwf + og*36864 + ((r*2+c02)*2+t)*1024 + (quad*16+l16)*16
//   (= lane*16, HW lane order): byte e holds channel c02*64+quad*16+e of
//   o = og*32+t*16+l16 at tap r = kh*3+kw. Wave chunk per (r,c02,t) = 1KB.
__global__ __launch_bounds__(256) void quant_w_kernel(
    const float* __restrict__ w, const float* __restrict__ sxp,
    char* __restrict__ qwf, float* __restrict__ alpha) {
  __shared__ float wf[1152];
  __shared__ float red[256];
  const int o = blockIdx.x;
  const int tid = threadIdx.x;
  const float* wrow = w + (size_t)o * 1152;
  float m = 0.f;
  for (int i = tid; i < 288; i += 256) {
    const float4 v = ((const float4*)wrow)[i];
    ((float4*)wf)[i] = v;
    m = fmaxf(m, fmaxf(fmaxf(fabsf(v.x), fabsf(v.y)),
                       fmaxf(fabsf(v.z), fabsf(v.w))));
  }
  red[tid] = m;
  __syncthreads();
  for (int s = 128; s > 0; s >>= 1) {
    if (tid < s) red[tid] = fmaxf(red[tid], red[tid + s]);
    __syncthreads();
  }
  const float sc = red[0] / 127.0f;   // max/QMAX, fp32, matches reference
  if (tid == 0) alpha[o] = sc * sxp[0];
  if (tid < 72) {   // r = tid/8, c02 = (tid>>2)&1, quad = tid&3
    const int r = tid >> 3, c02 = (tid >> 2) & 1, quad = tid & 3;
    const int og = o >> 5, t = (o >> 4) & 1, l16 = o & 15;
    int4v pk;
#pragma unroll
    for (int d = 0; d < 4; ++d) {
      unsigned int p = 0;
#pragma unroll
      for (int k = 0; k < 4; ++k) {
        const int c = c02 * 64 + quad * 16 + d * 4 + k;
        const int q =
            (int)fminf(127.f, fmaxf(-127.f, rintf(wf[c * 9 + r] / sc)));
        p |= ((unsigned int)(q & 255)) << (8 * k);
      }
      pk[d] = (int)p;
    }
    *(int4v*)(qwf + (size_t)og * 36864 + ((r * 2 + c02) * 2 + t) * 1024 +
              (quad * 16 + l16) * 16) = pk;   // HW lane order (R16 fix)
  }
}

// ---------------- kernel 2: x quantization -> swizzled im2col rows ---------
// qxp byte ((b*56+h)*56 + w)*128 + j holds q(x[b][ j^(((w+1)&7)<<4) ][h][w]).
__global__ __launch_bounds__(256) void quant_x_kernel(
    const float* __restrict__ x, const float* __restrict__ sxp,
    unsigned int* __restrict__ qxp) {
  __shared__ char ldsA[128 * 60];   // [c][w] quantized bytes, stride 60
  const int row = blockIdx.x;       // b*56 + h
  const int b = row / 56, h = row % 56;
  const float sx = sxp[0];
  for (int i = threadIdx.x; i < 1792; i += 256) {
    const int c = i / 14, f = i % 14;
    const float4 v =
        *(const float4*)(x + (((size_t)b * 128 + c) * 56 + h) * 56 + 4 * f);
    unsigned int pk;
    pk  = (unsigned int)((int)fminf(127.f, fmaxf(-127.f, rintf(v.x / sx))) & 255);
    pk |= ((unsigned int)((int)fminf(127.f, fmaxf(-127.f, rintf(v.y / sx))) & 255)) << 8;
    pk |= ((unsigned int)((int)fminf(127.f, fmaxf(-127.f, rintf(v.z / sx))) & 255)) << 16;
    pk |= ((unsigned int)((int)fminf(127.f, fmaxf(-127.f, rintf(v.w / sx))) & 255)) << 24;
    *(unsigned int*)(ldsA + c * 60 + 4 * f) = pk;
  }
  __syncthreads();
  unsigned int* orow = qxp + (size_t)row * 56 * 32;
  for (int i = threadIdx.x; i < 1792; i += 256) {
    const int w = i >> 5, jd = i & 31;
    // byte p of row w holds channel p ^ (((w+1)&7)<<4); dword-level: ph<<2
    const int c0 = (jd ^ (((w + 1) & 7) << 2)) << 2;  // channel base (4-run)
    unsigned int pk = 0;
#pragma unroll
    for (int k = 0; k < 4; ++k)
      pk |= ((unsigned int)(unsigned char)ldsA[(c0 + k) * 60 + w]) << (8 * k);
    orow[i] = pk;
  }
}

// ---------------- kernel 3: conv (16x16x64 i8, 8 waves, 256 o per block) ---
#define XSLAB 8448                  // 66 cols * 128B, contiguous (no pad)

__global__ __launch_bounds__(512, 4) void conv_kernel(
    const char* __restrict__ qxp, const char* __restrict__ qwf,
    const float* __restrict__ alpha, const float* __restrict__ bias,
    float* __restrict__ out) {
  __shared__ __attribute__((aligned(16))) char Xs8[3 * XSLAB];  // 25,344 B

  // chunked XCD swizzle: 1792 = 8*224; XCD (id&7) owns bi in [xcd*224,+224)
  const int id = blockIdx.x;        // 0..1791
  const int xcd = id & 7;
  const int bi = xcd * 224 + (id >> 3);
  const int b  = bi / 56;
  const int oh = bi % 56;
  const int tid = threadIdx.x;      // 0..511
  const int wave = tid >> 6, lane = tid & 63;   // wave = og, 0..7
  const int l16 = lane & 15, quad = lane >> 4;

  // A-operand base: per-lane int4v (16B); wave chunk per (r,c02,t) = 1KB.
  const int4v* wbA = (const int4v*)(qwf + (size_t)wave * 36864) + lane;
  int4v ap[2][2][2];                // [buf][c02][t]
#pragma unroll
  for (int c02 = 0; c02 < 2; ++c02)
#pragma unroll
    for (int t = 0; t < 2; ++t)
      ap[0][c02][t] = wbA[(size_t)(c02 * 2 + t) * 64];   // r = 0

  // ---- stage 3 input rows once for ALL 256 o (512 threads) ----
  for (int kh = 0; kh < 3; ++kh) {
    const int ih = oh - 1 + kh;
    char* slab = Xs8 + kh * XSLAB;
    if (ih >= 0 && ih < HH) {
      const char* src = qxp + ((size_t)b * 56 + ih) * 7168;
      if (tid < 448) gload_lds16(src + tid * 16, slab + 128 + tid * 16);
      for (int i = tid; i < 320; i += 512) {              // zero cols 0,57..65
        const int cg = i >> 5, dw = i & 31;
        const int col = (cg == 0) ? 0 : 56 + cg;
        ((unsigned int*)slab)[col * 32 + dw] = 0u;
      }
    } else {
      for (int i = tid; i < 2112; i += 512) ((unsigned int*)slab)[i] = 0u;
    }
  }

  int4v acc[2][4];
#pragma unroll
  for (int t = 0; t < 2; ++t)
#pragma unroll
    for (int u = 0; u < 4; ++u) acc[t][u] = (int4v){0, 0, 0, 0};

  __syncthreads();   // drains vmcnt (global_load_lds + ap[0]) + lgkm

  // ---- K-loop: 18 substeps (9 taps x 2 K64-chunks), B-pp, A-pp per tap ----
  int4v bops[2][4];
  {
    const int ph0 = (l16 & 7) << 4;         // g=0: kh=0, kw=0
    const int boff0 = (quad * 16) ^ ph0;    // c02=0
#pragma unroll
    for (int u = 0; u < 4; ++u)
      bops[0][u] = *(const int4v*)(Xs8 + (u * 16 + l16) * 128 + boff0);
  }
#pragma unroll
  for (int ss = 0; ss < 18; ++ss) {
    const int g = ss >> 1, c02 = ss & 1;
    // prefetch next substep's B fragments (static after unroll)
    if (ss + 1 < 18) {
      const int gn = (ss + 1) >> 1, cn = (ss + 1) & 1;
      const int khn = gn / 3, kwn = gn % 3;
      const char* Xkn = Xs8 + khn * XSLAB;
      const int phn = ((l16 + kwn) & 7) << 4;
      const int boffn = (cn * 64 + quad * 16) ^ phn;
#pragma unroll
      for (int u = 0; u < 4; ++u)
        bops[(ss + 1) & 1][u] =
            *(const int4v*)(Xkn + (u * 16 + l16 + kwn) * 128 + boffn);
    }
    // prefetch next tap's A fragments (once per g)
    if (c02 == 0 && g < 8) {
#pragma unroll
      for (int cc = 0; cc < 2; ++cc)
#pragma unroll
        for (int t = 0; t < 2; ++t)
          ap[(g + 1) & 1][cc][t] =
              wbA[(size_t)(((g + 1) * 2 + cc) * 2 + t) * 64];
    }
#pragma unroll
    for (int u = 0; u < 4; ++u) {
      acc[0][u] = __builtin_amdgcn_mfma_i32_16x16x64_i8(
          ap[g & 1][c02][0], bops[ss & 1][u], acc[0][u], 0, 0, 0);
      acc[1][u] = __builtin_amdgcn_mfma_i32_16x16x64_i8(
          ap[g & 1][c02][1], bops[ss & 1][u], acc[1][u], 0, 0, 0);
    }
  }

  // C/D layout (HW-verified, proven since R12): row = quad*4+r, col = l16
#pragma unroll
  for (int t = 0; t < 2; ++t) {
#pragma unroll
    for (int r = 0; r < 4; ++r) {
      const int o = wave * 32 + t * 16 + quad * 4 + r;
      const float al = alpha[o], bz = bias[o];
      float* orow = out + (((size_t)b * OCH + o) * HH + oh) * WW;
#pragma unroll
      for (int u = 0; u < 4; ++u) {
        const int ow = u * 16 + l16;
        if (ow < WW) orow[ow] = (float)acc[t][u][r] * al + bz;
      }
    }
  }
}

// ---------------- fallback: R5's proven fused kernel (ws-free) -------------
#define FAS_ROW 392
#define FXS_ROW 136
#define FLDS_XS (128 * FAS_ROW)
#define FLDS_SC (FLDS_XS + 66 * FXS_ROW)
#define FLDS_AL (FLDS_SC + 512)
#define FLDS_BI (FLDS_AL + 512)
#define FLDS_RED (FLDS_BI + 512)
#define FLDS_TOT (FLDS_RED + 1024)

__global__ __launch_bounds__(256) void conv_fused_kernel(
    const float* __restrict__ x, const float* __restrict__ w,
    const float* __restrict__ bias, const float* __restrict__ sxp,
    float* __restrict__ out) {
  __shared__ __attribute__((aligned(16))) char lds[FLDS_TOT];
  char* As8 = lds;
  char* Xs8 = lds + FLDS_XS;
  float* scaleS = (float*)(lds + FLDS_SC);
  float* alphaS = (float*)(lds + FLDS_AL);
  float* biasS  = (float*)(lds + FLDS_BI);
  float* red    = (float*)(lds + FLDS_RED);

  const int bi = blockIdx.x;
  const int b  = bi / 56;
  const int oh = bi % 56;
  const int o0 = blockIdx.y * 128;
  const int tid = threadIdx.x;
  const int wave = tid >> 6, lane = tid & 63;
  const int l16 = lane & 15, quad = lane >> 4;
  const float sx = sxp[0];

  typedef __attribute__((ext_vector_type(4))) int int4vf;
  int m_r[4], n_r[4];
  {
    int4vf zz = {0, 0, 0, 0};
    long a1 = 0, b1 = 0, a2 = 0, b2 = 0;
    if (quad == 0) { a1 = 1L; b1 = (long)(l16 + 1); a2 = (long)(l16 + 1); b2 = 1L; }
    int4vf d1 = __builtin_amdgcn_mfma_i32_16x16x32_i8(a1, b1, zz, 0, 0, 0);
    int4vf d2 = __builtin_amdgcn_mfma_i32_16x16x32_i8(a2, b2, zz, 0, 0, 0);
#pragma unroll
    for (int r = 0; r < 4; ++r) { n_r[r] = (d1[r] - 1) & 15; m_r[r] = (d2[r] - 1) & 15; }
  }
  {
    const int o = tid >> 1, half = tid & 1;
    const float4* p = (const float4*)(w + (size_t)(o0 + o) * 1152 + half * 576);
    float m = 0.f;
#pragma unroll 4
    for (int i = 0; i < 144; ++i) {
      const float4 v = p[i];
      m = fmaxf(m, fmaxf(fmaxf(fabsf(v.x), fabsf(v.y)), fmaxf(fabsf(v.z), fabsf(v.w))));
    }
    red[tid] = m;
  }
  __syncthreads();
  {
    const int o = tid >> 1;
    if ((tid & 1) == 0) {
      const float sc = fmaxf(red[2 * o], red[2 * o + 1]) / 127.0f;
      scaleS[o] = sc; alphaS[o] = sc * sx; biasS[o] = bias[o0 + o];
    }
  }
  int4vf acc[2][4];
#pragma unroll
  for (int t = 0; t < 2; ++t)
#pragma unroll
    for (int u = 0; u < 4; ++u) acc[t][u] = (int4vf){0, 0, 0, 0};

  for (int kh = 0; kh < 3; ++kh) {
    const int ih = oh - 1 + kh;
    const bool row_ok = (ih >= 0) && (ih < HH);
    __syncthreads();
    for (int idx = tid; idx < 66 * 128; idx += 256) {
      const int col = idx % 66, c = idx / 66, iw = col - 1;
      int q = 0;
      if (row_ok && iw >= 0 && iw < WW) {
        const float xv = x[(((size_t)b * CIN + c) * HH + ih) * WW + iw];
        q = (int)fminf(127.f, fmaxf(-127.f, rintf(xv / sx)));
      }
      Xs8[col * FXS_ROW + c] = (char)q;
    }
    for (int idx = tid; idx < 16384; idx += 256) {
      const int c = idx & 127, o = idx >> 7;
      const float s = scaleS[o];
      const float* wp = w + (size_t)(o0 + o) * 1152 + c * 9 + kh * 3;
#pragma unroll
      for (int kw = 0; kw < 3; ++kw) {
        const int q = (int)fminf(127.f, fmaxf(-127.f, rintf(wp[kw] / s)));
        As8[o * FAS_ROW + kw * 128 + c] = (char)q;
      }
    }
    __syncthreads();
    const int obase = wave * 32;
#pragma unroll
    for (int kw = 0; kw < 3; ++kw) {
#pragma unroll
      for (int c0 = 0; c0 < 128; c0 += 32) {
        long aop[2], bop[4];
#pragma unroll
        for (int t = 0; t < 2; ++t)
          aop[t] = *(const long*)(As8 + (obase + t * 16 + l16) * FAS_ROW + kw * 128 + c0 + quad * 8);
#pragma unroll
        for (int u = 0; u < 4; ++u)
          bop[u] = *(const long*)(Xs8 + (u * 16 + l16 + kw) * FXS_ROW + c0 + quad * 8);
#pragma unroll
        for (int t = 0; t < 2; ++t)
#pragma unroll
          for (int u = 0; u < 4; ++u)
            acc[t][u] = __builtin_amdgcn_mfma_i32_16x16x32_i8(aop[t], bop[u], acc[t][u], 0, 0, 0);
      }
    }
  }
#pragma unroll
  for (int t = 0; t < 2; ++t) {
#pragma unroll
    for (int u = 0; u < 4; ++u) {
#pragma unroll
      for (int r = 0; r < 4; ++r) {
        const int ol = wave * 32 + t * 16 + m_r[r];
        const int ow = u * 16 + n_r[r];
        if (ow < WW)
          out[(((size_t)b * OCH + o0 + ol) * HH + oh) * WW + ow] =
              (float)acc[t][u][r] * alphaS[ol] + biasS[ol];
      }
    }
  }
}

extern "C" void kernel_launch(void* const* d_in, const int* in_sizes, int n_in,
                              void* d_out, int out_size, void* d_ws, size_t ws_size,
                              hipStream_t stream) {
  const float *x = nullptr, *w = nullptr, *bias = nullptr, *sx = nullptr;
  for (int i = 0; i < n_in; ++i) {
    const int s = in_sizes[i];
    if (s == BATCH * CIN * HH * WW) x = (const float*)d_in[i];
    else if (s == OCH * CIN * 9)    w = (const float*)d_in[i];
    else if (s == OCH)              bias = (const float*)d_in[i];
    else if (s == 1)                sx = (const float*)d_in[i];
  }
  if (!x || !w || !bias || !sx) {
    x = (const float*)d_in[0]; w = (const float*)d_in[1];
    bias = (const float*)d_in[2]; sx = (const float*)d_in[3];
  }
  float* out = (float*)d_out;

  if (ws_size >= (size_t)WS_NEEDED) {
    unsigned int* qxp = (unsigned int*)d_ws;
    char* qwf = (char*)d_ws + QX_BYTES;
    float* alpha = (float*)((char*)d_ws + QX_BYTES + QW_BYTES);
    quant_w_kernel<<<OCH, 256, 0, stream>>>(w, sx, qwf, alpha);
    quant_x_kernel<<<BATCH * HH, 256, 0, stream>>>(x, sx, qxp);
    conv_kernel<<<BATCH * HH, 512, 0, stream>>>(
        (const char*)qxp, qwf, alpha, bias, out);
  } else {
    conv_fused_kernel<<<dim3(BATCH * HH, 2), 256, 0, stream>>>(x, w, bias, sx, out);
  }
}